// Round 8
// baseline (562.129 us; speedup 1.0000x reference)
//
#include <hip/hip_runtime.h>
#include <stdint.h>

typedef unsigned short u16;
typedef unsigned int u32;
typedef __attribute__((ext_vector_type(8))) short short8;
typedef __attribute__((ext_vector_type(4))) float floatx4;

#define BATCH   131072
#define NA      3
#define OBS     30
#define ACTD    9
#define HID     128
#define HEADS   4
#define HD      32
#define MB      16
#define ROWS    (MB*NA)     // 48
#define LDC     140         // 70 dwords == 6 mod 32: epilogue stores conflict-free, reads balanced
#define LDOA    72          // oa input tile stride
#define QSCALE  0.17677669529663687f
#define NTHREADS 512

// prepacked-weight offsets in d_ws, u16 units (fragment = 64 lanes x 8 bf16)
#define OFF_WO    0
#define OFF_WOA   12288
#define OFF_WQ    36864
#define OFF_WK    53248
#define OFF_WV    69632
#define OFF_WC1   86016
#define OFF_WC2   184320
#define PRE_TOTAL 190464

__device__ __forceinline__ u16 f2bf(float f) {          // round-nearest (ties up)
    union { float f; u32 u; } v; v.f = f;
    return (u16)((v.u + 0x8000u) >> 16);
}
// pack 2 f32 -> 2 bf16 in a u32 via v_perm (2 adds + 1 perm)
__device__ __forceinline__ u32 pk2(float a, float b) {
    union { float f; u32 u; } x, y; x.f = a; y.f = b;
    return __builtin_amdgcn_perm(y.u + 0x8000u, x.u + 0x8000u, 0x07060302u);
}
__device__ __forceinline__ float lo16f(u32 w) { union { u32 u; float f; } v; v.u = w << 16; return v.f; }
__device__ __forceinline__ float hi16f(u32 w) { union { u32 u; float f; } v; v.u = w & 0xffff0000u; return v.f; }
__device__ __forceinline__ float leaky(float x) { return fmaxf(x, 0.01f * x); }

// ------------- weight prepack: f32 [k][n] -> bf16 MFMA B-fragment order -------------
__global__ void prepack_kernel(const float* __restrict__ Wo,  const float* __restrict__ Woa,
                               const float* __restrict__ Wq,  const float* __restrict__ Wk,
                               const float* __restrict__ Wv,  const float* __restrict__ Wc1,
                               const float* __restrict__ Wc2, u16* __restrict__ out) {
    int i = blockIdx.x * blockDim.x + threadIdx.x;
    if (i >= PRE_TOTAL) return;
    const float* src; int K, KT, perA, base, Nsrc, Nlim; float scl = 1.f;
    if (i < OFF_WOA)      { src = Wo;  K = 30;  KT = 1; perA = 4096;  base = OFF_WO;  Nsrc = 128; Nlim = 128; }
    else if (i < OFF_WQ)  { src = Woa; K = 39;  KT = 2; perA = 8192;  base = OFF_WOA; Nsrc = 128; Nlim = 128; }
    else if (i < OFF_WK)  { src = Wq;  K = 128; KT = 4; perA = 16384; base = OFF_WQ;  Nsrc = 128; Nlim = 128; scl = QSCALE; }
    else if (i < OFF_WV)  { src = Wk;  K = 128; KT = 4; perA = 16384; base = OFF_WK;  Nsrc = 128; Nlim = 128; }
    else if (i < OFF_WC1) { src = Wv;  K = 128; KT = 4; perA = 16384; base = OFF_WV;  Nsrc = 128; Nlim = 128; }
    else if (i < OFF_WC2) { src = Wc1; K = 256; KT = 8; perA = 32768; base = OFF_WC1; Nsrc = 128; Nlim = 128; }
    else                  { src = Wc2; K = 128; KT = 4; perA = 2048;  base = OFF_WC2; Nsrc = 9;   Nlim = 9;   }
    int j = i - base;
    int agent = j / perA;
    int r = j - agent * perA;
    int e = r & 7, lane = (r >> 3) & 63, fk = r >> 9;
    int kt = fk % KT, nt = fk / KT;
    int n = nt * 16 + (lane & 15);
    int k = kt * 32 + (lane >> 4) * 8 + e;
    u16 v = 0;
    if (k < K && n < Nlim) v = f2bf(src[(agent * K + k) * Nsrc + n] * scl);
    out[i] = v;
}

// ---------------- fused forward: 512 threads (8 waves), 3 blocks/CU ----------------
__global__ __launch_bounds__(NTHREADS, 6) void fused_kernel(
    const float* __restrict__ obs, const float* __restrict__ act,
    const float* __restrict__ b_o, const float* __restrict__ b_oa,
    const float* __restrict__ bq,  const float* __restrict__ bk_, const float* __restrict__ bv,
    const float* __restrict__ bc1, const float* __restrict__ bc2,
    const u16* __restrict__ pre, float* __restrict__ out)
{
    __shared__ __align__(16) u16 s_mem[4 * ROWS * LDC];        // 53760 B -> 3 blk/CU
    u16* s_oemb  = s_mem;                    // o_emb (persistent)
    u16* s_oaemb = s_mem + ROWS * LDC;       // oa_emb -> attn_out
    u16* s_bufA  = s_mem + 2 * ROWS * LDC;   // oa-tile -> Q -> V
    u16* s_bufB  = s_mem + 3 * ROWS * LDC;   // K -> h

    const int tid  = threadIdx.x;
    const int wave = tid >> 6, lane = tid & 63;
    const int l15  = lane & 15, quad = lane >> 4;
    const int b0   = blockIdx.x * MB;
    const short8* preV = (const short8*)pre;

    // ---- stage 0: stage [obs|act|0] tile as packed u32 writes, layout [agent][MB][LDOA] ----
    for (int g = tid; g < ROWS * 15; g += NTHREADS) {          // obs k=0..29
        int r = g / 15, s = g - r * 15;
        int n = r / MB, bl = r - n * MB;
        const float* src = &obs[((b0 + bl) * NA + n) * OBS + 2 * s];
        *(u32*)&s_bufA[n * (MB * LDOA) + bl * LDOA + 2 * s] = pk2(src[0], src[1]);
    }
    for (int g = tid; g < ROWS * 5; g += NTHREADS) {           // act k=30..38, zero k=39
        int r = g / 5, s = g - r * 5;
        int n = r / MB, bl = r - n * MB;
        const float* src = &act[((b0 + bl) * NA + n) * ACTD + 2 * s];
        float v0 = src[0], v1 = (s < 4) ? src[1] : 0.f;
        *(u32*)&s_bufA[n * (MB * LDOA) + bl * LDOA + 30 + 2 * s] = pk2(v0, v1);
    }
    for (int g = tid; g < ROWS * 12; g += NTHREADS) {          // zero k=40..63
        int r = g / 12, s = g - r * 12;
        int n = r / MB, bl = r - n * MB;
        *(u32*)&s_bufA[n * (MB * LDOA) + bl * LDOA + 40 + 2 * s] = 0;
    }
    __syncthreads();

    // ---- stage 1: per-agent embeds, 24 jobs (osel, agent, nh2) over 8 waves ----
    for (int sj = wave; sj < 24; sj += 8) {
        int osel = sj / 12;             // 0: o_emb  1: oa_emb
        int rem = sj % 12, agent = rem >> 2, nh2 = rem & 3;
        int KTn = osel ? 2 : 1;
        const float* bias = osel ? b_oa : b_o;
        int preBase = osel ? (OFF_WOA / 8 + agent * 1024) : (OFF_WO / 8 + agent * 512);
        floatx4 acc[2] = {};
        for (int kt = 0; kt < KTn; kt++) {
            short8 a = *(const short8*)&s_bufA[agent * (MB * LDOA) + l15 * LDOA + kt * 32 + quad * 8];
            #pragma unroll
            for (int n2 = 0; n2 < 2; n2++) {
                int nt = nh2 * 2 + n2;
                short8 b = preV[preBase + (nt * KTn + kt) * 64 + lane];
                acc[n2] = __builtin_amdgcn_mfma_f32_16x16x32_bf16(a, b, acc[n2], 0, 0, 0);
            }
        }
        u16* dst = osel ? s_oaemb : s_oemb;
        #pragma unroll
        for (int n2 = 0; n2 < 2; n2++) {
            int col = (nh2 * 2 + n2) * 16 + l15;
            float bb = bias[agent * HID + col];
            #pragma unroll
            for (int rg = 0; rg < 4; rg++) {
                int m = quad * 4 + rg;
                dst[(m * NA + agent) * LDC + col] = f2bf(leaky(acc[n2][rg] + bb));
            }
        }
    }
    __syncthreads();

    // ---- stage 2: Q (scale folded into Wq) and K; exactly 8 jobs (proj, nh2) ----
    {
        int proj = wave >> 2, nh2 = wave & 3;   // w0-3: Q, w4-7: K
        const u16* Abuf = proj ? s_oaemb : s_oemb;
        int preBase = (proj ? OFF_WK : OFF_WQ) / 8;
        u16* dst = proj ? s_bufB : s_bufA;
        const float* bias = proj ? bk_ : bq;
        float bscl = proj ? 1.f : QSCALE;
        short8 wf[8];
        #pragma unroll
        for (int n2 = 0; n2 < 2; n2++)
            #pragma unroll
            for (int kt = 0; kt < 4; kt++)
                wf[n2 * 4 + kt] = preV[preBase + ((nh2 * 2 + n2) * 4 + kt) * 64 + lane];
        for (int mt = 0; mt < 3; mt++) {
            short8 xa[4];
            #pragma unroll
            for (int kt = 0; kt < 4; kt++)
                xa[kt] = *(const short8*)&Abuf[(mt * 16 + l15) * LDC + kt * 32 + quad * 8];
            floatx4 acc[2] = {};
            #pragma unroll
            for (int n2 = 0; n2 < 2; n2++)
                #pragma unroll
                for (int kt = 0; kt < 4; kt++)
                    acc[n2] = __builtin_amdgcn_mfma_f32_16x16x32_bf16(xa[kt], wf[n2 * 4 + kt], acc[n2], 0, 0, 0);
            #pragma unroll
            for (int n2 = 0; n2 < 2; n2++) {
                int col = (nh2 * 2 + n2) * 16 + l15;
                float bb = bias[col] * bscl;
                #pragma unroll
                for (int rg = 0; rg < 4; rg++) {
                    int m = mt * 16 + quad * 4 + rg;
                    dst[m * LDC + col] = f2bf(acc[n2][rg] + bb);
                }
            }
        }
    }
    __syncthreads();

    // ---- stage 3a: masked softmax, off-diagonal only; probs stay in registers ----
    float2 prob = make_float2(0.f, 0.f);
    int e3 = 0, h3 = 0, n3 = 0, m30 = 0, m31 = 0;
    const bool attn_thread = (tid < MB * HEADS * NA);
    if (attn_thread) {
        int r = tid;
        e3 = r / (HEADS * NA); r -= e3 * HEADS * NA; h3 = r / NA; n3 = r - h3 * NA;
        m30 = (n3 == 0) ? 1 : 0;
        m31 = (n3 == 2) ? 1 : 2;
        const uint4* qp  = (const uint4*)&s_bufA[(e3 * NA + n3) * LDC + h3 * HD];
        const uint4* kp0 = (const uint4*)&s_bufB[(e3 * NA + m30) * LDC + h3 * HD];
        const uint4* kp1 = (const uint4*)&s_bufB[(e3 * NA + m31) * LDC + h3 * HD];
        float s0 = 0.f, s1 = 0.f;
        #pragma unroll
        for (int c = 0; c < 4; c++) {
            uint4 qw = qp[c], aw = kp0[c], bw = kp1[c];
            u32 qv[4] = {qw.x, qw.y, qw.z, qw.w};
            u32 av[4] = {aw.x, aw.y, aw.z, aw.w};
            u32 bv_[4] = {bw.x, bw.y, bw.z, bw.w};
            #pragma unroll
            for (int j = 0; j < 4; j++) {
                float ql = lo16f(qv[j]), qh = hi16f(qv[j]);
                s0 += ql * lo16f(av[j]) + qh * hi16f(av[j]);
                s1 += ql * lo16f(bv_[j]) + qh * hi16f(bv_[j]);
            }
        }
        float mx = fmaxf(s0, s1);
        float p0 = __expf(s0 - mx), p1 = __expf(s1 - mx);
        float inv = 1.f / (p0 + p1);
        prob = make_float2(p0 * inv, p1 * inv);
    }
    __syncthreads();

    // ---- stage 3b: V = oa_emb @ Wv + bv ; 8 jobs (nt = wave) ----
    {
        int nt = wave;
        short8 wf[4];
        #pragma unroll
        for (int kt = 0; kt < 4; kt++)
            wf[kt] = preV[OFF_WV / 8 + (nt * 4 + kt) * 64 + lane];
        for (int mt = 0; mt < 3; mt++) {
            short8 xa[4];
            #pragma unroll
            for (int kt = 0; kt < 4; kt++)
                xa[kt] = *(const short8*)&s_oaemb[(mt * 16 + l15) * LDC + kt * 32 + quad * 8];
            floatx4 acc = {};
            #pragma unroll
            for (int kt = 0; kt < 4; kt++)
                acc = __builtin_amdgcn_mfma_f32_16x16x32_bf16(xa[kt], wf[kt], acc, 0, 0, 0);
            int col = nt * 16 + l15;
            float bb = bv[col];
            #pragma unroll
            for (int rg = 0; rg < 4; rg++) {
                int m = mt * 16 + quad * 4 + rg;
                s_bufA[m * LDC + col] = f2bf(acc[rg] + bb);
            }
        }
    }
    __syncthreads();

    // ---- stage 3c: attn_out = probs @ V (probs from registers) ----
    if (attn_thread) {
        const uint4* v0p = (const uint4*)&s_bufA[(e3 * NA + m30) * LDC + h3 * HD];
        const uint4* v1p = (const uint4*)&s_bufA[(e3 * NA + m31) * LDC + h3 * HD];
        uint4* dst = (uint4*)&s_oaemb[(e3 * NA + n3) * LDC + h3 * HD];
        #pragma unroll
        for (int c = 0; c < 4; c++) {
            uint4 aw = v0p[c], bw = v1p[c], ow;
            u32 av[4] = {aw.x, aw.y, aw.z, aw.w};
            u32 bv_[4] = {bw.x, bw.y, bw.z, bw.w};
            u32 ov[4];
            #pragma unroll
            for (int j = 0; j < 4; j++) {
                float lo = prob.x * lo16f(av[j]) + prob.y * lo16f(bv_[j]);
                float hi = prob.x * hi16f(av[j]) + prob.y * hi16f(bv_[j]);
                ov[j] = pk2(lo, hi);
            }
            ow.x = ov[0]; ow.y = ov[1]; ow.z = ov[2]; ow.w = ov[3];
            dst[c] = ow;
        }
    }
    __syncthreads();

    // ---- stage 4: critic layer 1, 24 jobs (agent, nt); K-split concat ----
    for (int sj = wave; sj < 24; sj += 8) {
        int agent = sj >> 3, nt = sj & 7;
        floatx4 acc = {};
        for (int kt = 0; kt < 8; kt++) {
            const u16* A = (kt < 4) ? s_oemb : s_oaemb;
            int kk = (kt & 3) * 32 + quad * 8;
            short8 a = *(const short8*)&A[(l15 * NA + agent) * LDC + kk];
            short8 b = preV[OFF_WC1 / 8 + agent * 4096 + (nt * 8 + kt) * 64 + lane];
            acc = __builtin_amdgcn_mfma_f32_16x16x32_bf16(a, b, acc, 0, 0, 0);
        }
        int col = nt * 16 + l15;
        float bb = bc1[agent * HID + col];
        #pragma unroll
        for (int rg = 0; rg < 4; rg++) {
            int m = quad * 4 + rg;
            s_bufB[(m * NA + agent) * LDC + col] = f2bf(leaky(acc[rg] + bb));
        }
    }
    __syncthreads();

    // ---- stage 5: critic layer 2 -> q_values, f32 out ----
    if (wave < NA) {
        int agent = wave;
        floatx4 acc = {};
        #pragma unroll
        for (int kt = 0; kt < 4; kt++) {
            short8 a = *(const short8*)&s_bufB[(l15 * NA + agent) * LDC + kt * 32 + quad * 8];
            short8 b = preV[OFF_WC2 / 8 + agent * 256 + kt * 64 + lane];
            acc = __builtin_amdgcn_mfma_f32_16x16x32_bf16(a, b, acc, 0, 0, 0);
        }
        int col = l15;
        if (col < ACTD) {
            float bb = bc2[agent * ACTD + col];
            #pragma unroll
            for (int rg = 0; rg < 4; rg++) {
                int m = quad * 4 + rg;
                out[((b0 + m) * NA + agent) * ACTD + col] = acc[rg] + bb;
            }
        }
    }
}

extern "C" void kernel_launch(void* const* d_in, const int* in_sizes, int n_in,
                              void* d_out, int out_size, void* d_ws, size_t ws_size,
                              hipStream_t stream) {
    const float* obs = (const float*)d_in[0];
    const float* act = (const float*)d_in[1];
    const float* Wo  = (const float*)d_in[2];
    const float* bo  = (const float*)d_in[3];
    const float* Woa = (const float*)d_in[4];
    const float* boa = (const float*)d_in[5];
    const float* Wq  = (const float*)d_in[6];
    const float* bq  = (const float*)d_in[7];
    const float* Wk  = (const float*)d_in[8];
    const float* bk  = (const float*)d_in[9];
    const float* Wv  = (const float*)d_in[10];
    const float* bv  = (const float*)d_in[11];
    const float* Wc1 = (const float*)d_in[12];
    const float* bc1 = (const float*)d_in[13];
    const float* Wc2 = (const float*)d_in[14];
    const float* bc2 = (const float*)d_in[15];
    u16* pre = (u16*)d_ws;   // needs 380928 B of workspace

    prepack_kernel<<<(PRE_TOTAL + 255) / 256, 256, 0, stream>>>(Wo, Woa, Wq, Wk, Wv, Wc1, Wc2, pre);
    fused_kernel<<<BATCH / MB, NTHREADS, 0, stream>>>(obs, act, bo, boa, bq, bk, bv, bc1, bc2, pre,
                                                      (float*)d_out);
}

// Round 9
// 262.044 us; speedup vs baseline: 2.1452x; 2.1452x over previous
//
#include <hip/hip_runtime.h>
#include <stdint.h>

typedef unsigned short u16;
typedef unsigned int u32;
typedef __attribute__((ext_vector_type(8))) short short8;
typedef __attribute__((ext_vector_type(4))) float floatx4;

#define BATCH   131072
#define NA      3
#define OBS     30
#define ACTD    9
#define HID     128
#define HEADS   4
#define HD      32
#define MB      16
#define ROWS    (MB*NA)     // 48
#define LDC     136         // 272 B row stride: 16B-aligned (b128 ok); conflicts fixed by row perm
#define LDOA    72          // oa input tile stride
#define QSCALE  0.17677669529663687f
#define NTHREADS 512

// prepacked-weight offsets in d_ws, u16 units (fragment = 64 lanes x 8 bf16)
#define OFF_WO    0
#define OFF_WOA   12288
#define OFF_WQ    36864
#define OFF_WK    53248
#define OFF_WV    69632
#define OFF_WC1   86016
#define OFF_WC2   184320
#define PRE_TOTAL 190464

__device__ __forceinline__ u16 f2bf(float f) {          // round-nearest (ties up)
    union { float f; u32 u; } v; v.f = f;
    return (u16)((v.u + 0x8000u) >> 16);
}
// pack 2 f32 -> 2 bf16 in a u32 via v_perm (2 adds + 1 perm)
__device__ __forceinline__ u32 pk2(float a, float b) {
    union { float f; u32 u; } x, y; x.f = a; y.f = b;
    return __builtin_amdgcn_perm(y.u + 0x8000u, x.u + 0x8000u, 0x07060302u);
}
__device__ __forceinline__ float lo16f(u32 w) { union { u32 u; float f; } v; v.u = w << 16; return v.f; }
__device__ __forceinline__ float hi16f(u32 w) { union { u32 u; float f; } v; v.u = w & 0xffff0000u; return v.f; }
__device__ __forceinline__ float leaky(float x) { return fmaxf(x, 0.01f * x); }
// within-16 physical row permutation: m=q*4+rg -> 2q + (rg&1) + 8*(rg>>1)  (bijection)
__device__ __forceinline__ int permrow(int m) {
    return 2 * (m >> 2) + (m & 1) + ((m & 2) << 2);
}

// ------------- weight prepack: f32 [k][n] -> bf16 MFMA B-fragment order -------------
__global__ void prepack_kernel(const float* __restrict__ Wo,  const float* __restrict__ Woa,
                               const float* __restrict__ Wq,  const float* __restrict__ Wk,
                               const float* __restrict__ Wv,  const float* __restrict__ Wc1,
                               const float* __restrict__ Wc2, u16* __restrict__ out) {
    int i = blockIdx.x * blockDim.x + threadIdx.x;
    if (i >= PRE_TOTAL) return;
    const float* src; int K, KT, perA, base, Nsrc, Nlim; float scl = 1.f;
    if (i < OFF_WOA)      { src = Wo;  K = 30;  KT = 1; perA = 4096;  base = OFF_WO;  Nsrc = 128; Nlim = 128; }
    else if (i < OFF_WQ)  { src = Woa; K = 39;  KT = 2; perA = 8192;  base = OFF_WOA; Nsrc = 128; Nlim = 128; }
    else if (i < OFF_WK)  { src = Wq;  K = 128; KT = 4; perA = 16384; base = OFF_WQ;  Nsrc = 128; Nlim = 128; scl = QSCALE; }
    else if (i < OFF_WV)  { src = Wk;  K = 128; KT = 4; perA = 16384; base = OFF_WK;  Nsrc = 128; Nlim = 128; }
    else if (i < OFF_WC1) { src = Wv;  K = 128; KT = 4; perA = 16384; base = OFF_WV;  Nsrc = 128; Nlim = 128; }
    else if (i < OFF_WC2) { src = Wc1; K = 256; KT = 8; perA = 32768; base = OFF_WC1; Nsrc = 128; Nlim = 128; }
    else                  { src = Wc2; K = 128; KT = 4; perA = 2048;  base = OFF_WC2; Nsrc = 9;   Nlim = 9;   }
    int j = i - base;
    int agent = j / perA;
    int r = j - agent * perA;
    int e = r & 7, lane = (r >> 3) & 63, fk = r >> 9;
    int kt = fk % KT, nt = fk / KT;
    int n = nt * 16 + (lane & 15);
    int k = kt * 32 + (lane >> 4) * 8 + e;
    u16 v = 0;
    if (k < K && n < Nlim) v = f2bf(src[(agent * K + k) * Nsrc + n] * scl);
    out[i] = v;
}

// -------- fused forward: agent-major activation buffers, permuted rows (conflict-free stores) --------
__global__ __launch_bounds__(NTHREADS, 6) void fused_kernel(
    const float* __restrict__ obs, const float* __restrict__ act,
    const float* __restrict__ b_o, const float* __restrict__ b_oa,
    const float* __restrict__ bq,  const float* __restrict__ bk_, const float* __restrict__ bv,
    const float* __restrict__ bc1, const float* __restrict__ bc2,
    const u16* __restrict__ pre, float* __restrict__ out)
{
    __shared__ __align__(16) u16 s_mem[4 * ROWS * LDC];        // 52224 B -> 3 blk/CU
    u16* s_oemb  = s_mem;                    // o_emb (persistent)          [agent][perm(e)]
    u16* s_oaemb = s_mem + ROWS * LDC;       // oa_emb -> attn_out          [agent][perm(e)]
    u16* s_bufA  = s_mem + 2 * ROWS * LDC;   // oa-tile -> Q -> V           [agent][perm(e)]
    u16* s_bufB  = s_mem + 3 * ROWS * LDC;   // K -> h                      [agent][perm(e)]

    const int tid  = threadIdx.x;
    const int wave = tid >> 6, lane = tid & 63;
    const int l15  = lane & 15, quad = lane >> 4;
    const int pl   = permrow(l15);           // read-side physical row for logical l15
    const int b0   = blockIdx.x * MB;
    const short8* preV = (const short8*)pre;

    // ---- stage 0: stage [obs|act|0] tile as packed u32 writes, layout [agent][MB][LDOA] ----
    for (int g = tid; g < ROWS * 15; g += NTHREADS) {          // obs k=0..29
        int r = g / 15, s = g - r * 15;
        int n = r / MB, bl = r - n * MB;
        const float* src = &obs[((b0 + bl) * NA + n) * OBS + 2 * s];
        *(u32*)&s_bufA[n * (MB * LDOA) + bl * LDOA + 2 * s] = pk2(src[0], src[1]);
    }
    for (int g = tid; g < ROWS * 5; g += NTHREADS) {           // act k=30..38, zero k=39
        int r = g / 5, s = g - r * 5;
        int n = r / MB, bl = r - n * MB;
        const float* src = &act[((b0 + bl) * NA + n) * ACTD + 2 * s];
        float v0 = src[0], v1 = (s < 4) ? src[1] : 0.f;
        *(u32*)&s_bufA[n * (MB * LDOA) + bl * LDOA + 30 + 2 * s] = pk2(v0, v1);
    }
    for (int g = tid; g < ROWS * 12; g += NTHREADS) {          // zero k=40..63
        int r = g / 12, s = g - r * 12;
        int n = r / MB, bl = r - n * MB;
        *(u32*)&s_bufA[n * (MB * LDOA) + bl * LDOA + 40 + 2 * s] = 0;
    }
    __syncthreads();

    // ---- stage 1: per-agent embeds, 24 jobs (osel, agent, nh2); permuted agent-major store ----
    for (int sj = wave; sj < 24; sj += 8) {
        int osel = sj / 12;             // 0: o_emb  1: oa_emb
        int rem = sj % 12, agent = rem >> 2, nh2 = rem & 3;
        int KTn = osel ? 2 : 1;
        const float* bias = osel ? b_oa : b_o;
        int preBase = osel ? (OFF_WOA / 8 + agent * 1024) : (OFF_WO / 8 + agent * 512);
        floatx4 acc[2] = {};
        for (int kt = 0; kt < KTn; kt++) {
            short8 a = *(const short8*)&s_bufA[agent * (MB * LDOA) + l15 * LDOA + kt * 32 + quad * 8];
            #pragma unroll
            for (int n2 = 0; n2 < 2; n2++) {
                int nt = nh2 * 2 + n2;
                short8 b = preV[preBase + (nt * KTn + kt) * 64 + lane];
                acc[n2] = __builtin_amdgcn_mfma_f32_16x16x32_bf16(a, b, acc[n2], 0, 0, 0);
            }
        }
        u16* dst = osel ? s_oaemb : s_oemb;
        #pragma unroll
        for (int n2 = 0; n2 < 2; n2++) {
            int col = (nh2 * 2 + n2) * 16 + l15;
            float bb = bias[agent * HID + col];
            #pragma unroll
            for (int rg = 0; rg < 4; rg++) {
                int pr = 2 * quad + (rg & 1) + ((rg & 2) << 2);   // perm(quad*4+rg)
                dst[(agent * 16 + pr) * LDC + col] = f2bf(leaky(acc[n2][rg] + bb));
            }
        }
    }
    __syncthreads();

    // ---- stage 2: Q (scale folded into Wq) and K; 8 jobs (proj, nh2); permuted rows ----
    {
        int proj = wave >> 2, nh2 = wave & 3;   // w0-3: Q, w4-7: K
        const u16* Abuf = proj ? s_oaemb : s_oemb;
        int preBase = (proj ? OFF_WK : OFF_WQ) / 8;
        u16* dst = proj ? s_bufB : s_bufA;
        const float* bias = proj ? bk_ : bq;
        float bscl = proj ? 1.f : QSCALE;
        short8 wf[8];
        #pragma unroll
        for (int n2 = 0; n2 < 2; n2++)
            #pragma unroll
            for (int kt = 0; kt < 4; kt++)
                wf[n2 * 4 + kt] = preV[preBase + ((nh2 * 2 + n2) * 4 + kt) * 64 + lane];
        for (int mt = 0; mt < 3; mt++) {
            short8 xa[4];
            #pragma unroll
            for (int kt = 0; kt < 4; kt++)
                xa[kt] = *(const short8*)&Abuf[(mt * 16 + pl) * LDC + kt * 32 + quad * 8];
            floatx4 acc[2] = {};
            #pragma unroll
            for (int n2 = 0; n2 < 2; n2++)
                #pragma unroll
                for (int kt = 0; kt < 4; kt++)
                    acc[n2] = __builtin_amdgcn_mfma_f32_16x16x32_bf16(xa[kt], wf[n2 * 4 + kt], acc[n2], 0, 0, 0);
            #pragma unroll
            for (int n2 = 0; n2 < 2; n2++) {
                int col = (nh2 * 2 + n2) * 16 + l15;
                float bb = bias[col] * bscl;
                #pragma unroll
                for (int rg = 0; rg < 4; rg++) {
                    int pr = 2 * quad + (rg & 1) + ((rg & 2) << 2);
                    dst[(mt * 16 + pr) * LDC + col] = f2bf(acc[n2][rg] + bb);
                }
            }
        }
    }
    __syncthreads();

    // ---- stage 3a: masked softmax, off-diagonal only; probs stay in registers ----
    float2 prob = make_float2(0.f, 0.f);
    int pe3 = 0, h3 = 0, n3 = 0, m30 = 0, m31 = 0;
    const bool attn_thread = (tid < MB * HEADS * NA);
    if (attn_thread) {
        int r = tid;
        int e3 = r / (HEADS * NA); r -= e3 * HEADS * NA; h3 = r / NA; n3 = r - h3 * NA;
        pe3 = permrow(e3);
        m30 = (n3 == 0) ? 1 : 0;
        m31 = (n3 == 2) ? 1 : 2;
        const uint4* qp  = (const uint4*)&s_bufA[(n3 * 16 + pe3) * LDC + h3 * HD];
        const uint4* kp0 = (const uint4*)&s_bufB[(m30 * 16 + pe3) * LDC + h3 * HD];
        const uint4* kp1 = (const uint4*)&s_bufB[(m31 * 16 + pe3) * LDC + h3 * HD];
        float s0 = 0.f, s1 = 0.f;
        #pragma unroll
        for (int c = 0; c < 4; c++) {
            uint4 qw = qp[c], aw = kp0[c], bw = kp1[c];
            u32 qv[4] = {qw.x, qw.y, qw.z, qw.w};
            u32 av[4] = {aw.x, aw.y, aw.z, aw.w};
            u32 bv_[4] = {bw.x, bw.y, bw.z, bw.w};
            #pragma unroll
            for (int j = 0; j < 4; j++) {
                float ql = lo16f(qv[j]), qh = hi16f(qv[j]);
                s0 += ql * lo16f(av[j]) + qh * hi16f(av[j]);
                s1 += ql * lo16f(bv_[j]) + qh * hi16f(bv_[j]);
            }
        }
        float mx = fmaxf(s0, s1);
        float p0 = __expf(s0 - mx), p1 = __expf(s1 - mx);
        float inv = 1.f / (p0 + p1);
        prob = make_float2(p0 * inv, p1 * inv);
    }
    __syncthreads();

    // ---- stage 3b: V = oa_emb @ Wv + bv ; 8 jobs (nt = wave); permuted rows ----
    {
        int nt = wave;
        short8 wf[4];
        #pragma unroll
        for (int kt = 0; kt < 4; kt++)
            wf[kt] = preV[OFF_WV / 8 + (nt * 4 + kt) * 64 + lane];
        for (int mt = 0; mt < 3; mt++) {
            short8 xa[4];
            #pragma unroll
            for (int kt = 0; kt < 4; kt++)
                xa[kt] = *(const short8*)&s_oaemb[(mt * 16 + pl) * LDC + kt * 32 + quad * 8];
            floatx4 acc = {};
            #pragma unroll
            for (int kt = 0; kt < 4; kt++)
                acc = __builtin_amdgcn_mfma_f32_16x16x32_bf16(xa[kt], wf[kt], acc, 0, 0, 0);
            int col = nt * 16 + l15;
            float bb = bv[col];
            #pragma unroll
            for (int rg = 0; rg < 4; rg++) {
                int pr = 2 * quad + (rg & 1) + ((rg & 2) << 2);
                s_bufA[(mt * 16 + pr) * LDC + col] = f2bf(acc[rg] + bb);
            }
        }
    }
    __syncthreads();

    // ---- stage 3c: attn_out = probs @ V (probs from registers); permuted rows ----
    if (attn_thread) {
        const uint4* v0p = (const uint4*)&s_bufA[(m30 * 16 + pe3) * LDC + h3 * HD];
        const uint4* v1p = (const uint4*)&s_bufA[(m31 * 16 + pe3) * LDC + h3 * HD];
        uint4* dst = (uint4*)&s_oaemb[(n3 * 16 + pe3) * LDC + h3 * HD];
        #pragma unroll
        for (int c = 0; c < 4; c++) {
            uint4 aw = v0p[c], bw = v1p[c], ow;
            u32 av[4] = {aw.x, aw.y, aw.z, aw.w};
            u32 bv_[4] = {bw.x, bw.y, bw.z, bw.w};
            u32 ov[4];
            #pragma unroll
            for (int j = 0; j < 4; j++) {
                float lo = prob.x * lo16f(av[j]) + prob.y * lo16f(bv_[j]);
                float hi = prob.x * hi16f(av[j]) + prob.y * hi16f(bv_[j]);
                ov[j] = pk2(lo, hi);
            }
            ow.x = ov[0]; ow.y = ov[1]; ow.z = ov[2]; ow.w = ov[3];
            dst[c] = ow;
        }
    }
    __syncthreads();

    // ---- stage 4: critic layer 1, 24 jobs (agent, nt); K-split concat; permuted rows ----
    for (int sj = wave; sj < 24; sj += 8) {
        int agent = sj >> 3, nt = sj & 7;
        floatx4 acc = {};
        for (int kt = 0; kt < 8; kt++) {
            const u16* A = (kt < 4) ? s_oemb : s_oaemb;
            int kk = (kt & 3) * 32 + quad * 8;
            short8 a = *(const short8*)&A[(agent * 16 + pl) * LDC + kk];
            short8 b = preV[OFF_WC1 / 8 + agent * 4096 + (nt * 8 + kt) * 64 + lane];
            acc = __builtin_amdgcn_mfma_f32_16x16x32_bf16(a, b, acc, 0, 0, 0);
        }
        int col = nt * 16 + l15;
        float bb = bc1[agent * HID + col];
        #pragma unroll
        for (int rg = 0; rg < 4; rg++) {
            int pr = 2 * quad + (rg & 1) + ((rg & 2) << 2);
            s_bufB[(agent * 16 + pr) * LDC + col] = f2bf(leaky(acc[rg] + bb));
        }
    }
    __syncthreads();

    // ---- stage 5: critic layer 2 -> q_values, f32 out ----
    if (wave < NA) {
        int agent = wave;
        floatx4 acc = {};
        #pragma unroll
        for (int kt = 0; kt < 4; kt++) {
            short8 a = *(const short8*)&s_bufB[(agent * 16 + pl) * LDC + kt * 32 + quad * 8];
            short8 b = preV[OFF_WC2 / 8 + agent * 256 + kt * 64 + lane];
            acc = __builtin_amdgcn_mfma_f32_16x16x32_bf16(a, b, acc, 0, 0, 0);
        }
        int col = l15;
        if (col < ACTD) {
            float bb = bc2[agent * ACTD + col];
            #pragma unroll
            for (int rg = 0; rg < 4; rg++) {
                int m = quad * 4 + rg;   // D rows are logical batch elems
                out[((b0 + m) * NA + agent) * ACTD + col] = acc[rg] + bb;
            }
        }
    }
}

extern "C" void kernel_launch(void* const* d_in, const int* in_sizes, int n_in,
                              void* d_out, int out_size, void* d_ws, size_t ws_size,
                              hipStream_t stream) {
    const float* obs = (const float*)d_in[0];
    const float* act = (const float*)d_in[1];
    const float* Wo  = (const float*)d_in[2];
    const float* bo  = (const float*)d_in[3];
    const float* Woa = (const float*)d_in[4];
    const float* boa = (const float*)d_in[5];
    const float* Wq  = (const float*)d_in[6];
    const float* bq  = (const float*)d_in[7];
    const float* Wk  = (const float*)d_in[8];
    const float* bk  = (const float*)d_in[9];
    const float* Wv  = (const float*)d_in[10];
    const float* bv  = (const float*)d_in[11];
    const float* Wc1 = (const float*)d_in[12];
    const float* bc1 = (const float*)d_in[13];
    const float* Wc2 = (const float*)d_in[14];
    const float* bc2 = (const float*)d_in[15];
    u16* pre = (u16*)d_ws;   // needs 380928 B of workspace

    prepack_kernel<<<(PRE_TOTAL + 255) / 256, 256, 0, stream>>>(Wo, Woa, Wq, Wk, Wv, Wc1, Wc2, pre);
    fused_kernel<<<BATCH / MB, NTHREADS, 0, stream>>>(obs, act, bo, boa, bq, bk, bv, bc1, bc2, pre,
                                                      (float*)d_out);
}